// Round 18
// baseline (244.111 us; speedup 1.0000x reference)
//
#include <hip/hip_runtime.h>

#define N_NODES 16384
#define N_EDGES 524288
#define TILE_I 16      // rows per block
#define TILE_J 2048    // 8 waves x 256 j
#define NBIN 256       // bins of 64 nodes
#define CAP 2560       // records per bin (avg 2048, sd ~45 -> 11 sigma)

typedef float f32x4 __attribute__((ext_vector_type(4)));

// ---------- Phase A: expand edges into per-bin record buffers ----------
__global__ __launch_bounds__(512) void binscatter_kernel(const int* __restrict__ eidx,
                                                         const float* __restrict__ x,
                                                         int* __restrict__ gcur,
                                                         float4* __restrict__ recs) {
    __shared__ int lcnt[NBIN];
    __shared__ int lbase[NBIN];
    const int tid = threadIdx.x;
    const int e = blockIdx.x * 512 + tid;

    if (tid < NBIN) lcnt[tid] = 0;
    __syncthreads();

    const int t = eidx[N_EDGES + e];
    const int s = eidx[e];
    const int bin = t >> 6;
    const float f0 = x[s * 3 + 0];
    const float f1 = x[s * 3 + 1];
    const float f2 = x[s * 3 + 2];
    atomicAdd(&lcnt[bin], 1);
    __syncthreads();

    if (tid < NBIN) {
        lbase[tid] = atomicAdd(&gcur[tid], lcnt[tid]);
        lcnt[tid] = 0;
    }
    __syncthreads();

    const int slot = lbase[bin] + atomicAdd(&lcnt[bin], 1);
    if (slot < CAP) {
        float4 r;
        r.x = __int_as_float(t);
        r.y = f0; r.z = f1; r.w = f2;
        recs[(size_t)bin * CAP + slot] = r;
    }
}

// ---------- Phase B: per-bin LDS reduction + fused GIN MLP ----------
__global__ __launch_bounds__(512) void binmlp_kernel(const float4* __restrict__ recs,
                                                     const int* __restrict__ gcur,
                                                     const float* __restrict__ x,
                                                     const float* __restrict__ W1,
                                                     const float* __restrict__ b1,
                                                     const float* __restrict__ W2,
                                                     const float* __restrict__ b2,
                                                     const float* __restrict__ eps_p,
                                                     float* __restrict__ h) {
    __shared__ float lagg[64 * 3];
    const int k = blockIdx.x;
    const int tid = threadIdx.x;

    if (tid < 192) lagg[tid] = 0.0f;
    __syncthreads();

    int cnt = gcur[k];
    if (cnt > CAP) cnt = CAP;
    for (int i = tid; i < cnt; i += 512) {
        const float4 r = recs[(size_t)k * CAP + i];
        const int d = __float_as_int(r.x) & 63;
        atomicAdd(&lagg[d * 3 + 0], r.y);
        atomicAdd(&lagg[d * 3 + 1], r.z);
        atomicAdd(&lagg[d * 3 + 2], r.w);
    }
    __syncthreads();

    if (tid < 64) {
        const int n = k * 64 + tid;
        const float se = 1.0f + eps_p[0];
        float z0 = se * x[n * 3 + 0] + lagg[tid * 3 + 0];
        float z1 = se * x[n * 3 + 1] + lagg[tid * 3 + 1];
        float z2 = se * x[n * 3 + 2] + lagg[tid * 3 + 2];
        float h1[16];
#pragma unroll
        for (int j = 0; j < 16; ++j) {
            float a = b1[j];
            a += z0 * W1[0 * 16 + j];
            a += z1 * W1[1 * 16 + j];
            a += z2 * W1[2 * 16 + j];
            h1[j] = fmaxf(a, 0.0f);
        }
        float4* h4 = (float4*)&h[(size_t)n * 16];
#pragma unroll
        for (int oq = 0; oq < 4; ++oq) {
            float4 o;
            float* op = (float*)&o;
#pragma unroll
            for (int c = 0; c < 4; ++c) {
                int oo = oq * 4 + c;
                float a = b2[oo];
#pragma unroll
                for (int j = 0; j < 16; ++j) a += h1[j] * W2[j * 16 + oo];
                op[c] = fmaxf(a, 0.0f);
            }
            h4[oq] = o;
        }
    }
}

// ---------- Fallback path (R16): SoA scatter + separate MLP ----------
__global__ void scatter_kernel(const int* __restrict__ eidx,
                               const float* __restrict__ x,
                               float* __restrict__ agg0,
                               float* __restrict__ agg1,
                               float* __restrict__ agg2) {
    int e = blockIdx.x * blockDim.x + threadIdx.x;
    if (e >= N_EDGES) return;
    int s = eidx[e];
    int t = eidx[N_EDGES + e];
    atomicAdd(&agg0[t], x[s * 3 + 0]);
    atomicAdd(&agg1[t], x[s * 3 + 1]);
    atomicAdd(&agg2[t], x[s * 3 + 2]);
}

__global__ void mlp_kernel(const float* __restrict__ x,
                           const float* __restrict__ agg0,
                           const float* __restrict__ agg1,
                           const float* __restrict__ agg2,
                           const float* __restrict__ W1,
                           const float* __restrict__ b1,
                           const float* __restrict__ W2,
                           const float* __restrict__ b2,
                           const float* __restrict__ eps_p,
                           float* __restrict__ h) {
    int n = blockIdx.x * blockDim.x + threadIdx.x;
    if (n >= N_NODES) return;
    float se = 1.0f + eps_p[0];
    float z0 = se * x[n * 3 + 0] + agg0[n];
    float z1 = se * x[n * 3 + 1] + agg1[n];
    float z2 = se * x[n * 3 + 2] + agg2[n];
    float h1[16];
#pragma unroll
    for (int j = 0; j < 16; ++j) {
        float a = b1[j];
        a += z0 * W1[0 * 16 + j];
        a += z1 * W1[1 * 16 + j];
        a += z2 * W1[2 * 16 + j];
        h1[j] = fmaxf(a, 0.0f);
    }
    float4* h4 = (float4*)&h[n * 16];
#pragma unroll
    for (int oq = 0; oq < 4; ++oq) {
        float4 o;
        float* op = (float*)&o;
#pragma unroll
        for (int c = 0; c < 4; ++c) {
            int oo = oq * 4 + c;
            float a = b2[oo];
#pragma unroll
            for (int j = 0; j < 16; ++j) a += h1[j] * W2[j * 16 + oo];
            op[c] = fmaxf(a, 0.0f);
        }
        h4[oq] = o;
    }
}

// ---------------- pairwise: out[i][j] = dot(h[i], h[j]) ----------------
// R7 structure; SINGLE CHANGE vs R17: plain stores instead of NT. The 8 KB
// contiguous row-spans of this layout are the shape where L2 write-
// aggregation (the fill kernel's 6.5 TB/s path) should work; the NT-vs-plain
// A/B was last run on the old 1 KB-interleaved layout (R4).
__global__ __launch_bounds__(512) void pairwise_kernel(const float* __restrict__ h,
                                                       float* __restrict__ out) {
    __shared__ float hi[TILE_I * 16];   // 1 KB
    const int i0 = (blockIdx.x >> 3) * TILE_I;
    const int j0 = (blockIdx.x & 7) * TILE_J;
    const int tid = threadIdx.x;
    const int wid = tid >> 6;
    const int lane = tid & 63;

    if (tid < TILE_I * 4) {
        ((f32x4*)hi)[tid] = ((const f32x4*)h)[(size_t)i0 * 4 + tid];
    }

    const int jbase = j0 + wid * 256 + lane * 4;
    const f32x4* hg = (const f32x4*)h;
    f32x4 hj[16];
#pragma unroll
    for (int jj = 0; jj < 4; ++jj) {
        const size_t jb4 = (size_t)(jbase + jj) * 4;
        f32x4 q0 = hg[jb4 + 0];
        f32x4 q1 = hg[jb4 + 1];
        f32x4 q2 = hg[jb4 + 2];
        f32x4 q3 = hg[jb4 + 3];
        hj[0][jj]  = q0.x;  hj[1][jj]  = q0.y;  hj[2][jj]  = q0.z;  hj[3][jj]  = q0.w;
        hj[4][jj]  = q1.x;  hj[5][jj]  = q1.y;  hj[6][jj]  = q1.z;  hj[7][jj]  = q1.w;
        hj[8][jj]  = q2.x;  hj[9][jj]  = q2.y;  hj[10][jj] = q2.z;  hj[11][jj] = q2.w;
        hj[12][jj] = q3.x;  hj[13][jj] = q3.y;  hj[14][jj] = q3.z;  hj[15][jj] = q3.w;
    }
    __syncthreads();

    f32x4* out4 = (f32x4*)out;
    const size_t obase = (size_t)i0 * (N_NODES / 4) + (size_t)(jbase >> 2);

#pragma unroll
    for (int r = 0; r < TILE_I; ++r) {
        const f32x4* hr = (const f32x4*)&hi[r * 16];
        f32x4 a0 = hr[0], a1 = hr[1], a2 = hr[2], a3 = hr[3];
        f32x4 acc = a0.x * hj[0];
        acc += a0.y * hj[1];
        acc += a0.z * hj[2];
        acc += a0.w * hj[3];
        acc += a1.x * hj[4];
        acc += a1.y * hj[5];
        acc += a1.z * hj[6];
        acc += a1.w * hj[7];
        acc += a2.x * hj[8];
        acc += a2.y * hj[9];
        acc += a2.z * hj[10];
        acc += a2.w * hj[11];
        acc += a3.x * hj[12];
        acc += a3.y * hj[13];
        acc += a3.z * hj[14];
        acc += a3.w * hj[15];
        out4[obase + (size_t)r * (N_NODES / 4)] = acc;
    }
}

extern "C" void kernel_launch(void* const* d_in, const int* in_sizes, int n_in,
                              void* d_out, int out_size, void* d_ws, size_t ws_size,
                              hipStream_t stream) {
    const float* node_feats = (const float*)d_in[0];
    const int*   edge_idx   = (const int*)d_in[1];
    const float* W1         = (const float*)d_in[2];
    const float* b1         = (const float*)d_in[3];
    const float* W2         = (const float*)d_in[4];
    const float* b2         = (const float*)d_in[5];
    const float* eps        = (const float*)d_in[6];
    float* out = (float*)d_out;

    // binned layout: gcur [256 ints] @0, h [1 MB] @4096, recs [10.5 MB] after
    int*    gcur = (int*)d_ws;
    float*  h    = (float*)((char*)d_ws + 4096);
    float4* recs = (float4*)((char*)d_ws + 4096 + (size_t)N_NODES * 16 * 4);
    const size_t need = 4096 + (size_t)N_NODES * 16 * 4
                      + (size_t)NBIN * CAP * sizeof(float4);

    if (ws_size >= need) {
        hipMemsetAsync(gcur, 0, NBIN * sizeof(int), stream);
        binscatter_kernel<<<N_EDGES / 512, 512, 0, stream>>>(edge_idx, node_feats,
                                                             gcur, recs);
        binmlp_kernel<<<NBIN, 512, 0, stream>>>(recs, gcur, node_feats,
                                                W1, b1, W2, b2, eps, h);
    } else {
        float* agg0 = (float*)((char*)d_ws + 4096 + (size_t)N_NODES * 16 * 4);
        float* agg1 = agg0 + N_NODES;
        float* agg2 = agg1 + N_NODES;
        hipMemsetAsync(agg0, 0, 3 * N_NODES * sizeof(float), stream);
        scatter_kernel<<<N_EDGES / 256, 256, 0, stream>>>(edge_idx, node_feats,
                                                          agg0, agg1, agg2);
        mlp_kernel<<<N_NODES / 256, 256, 0, stream>>>(node_feats, agg0, agg1, agg2,
                                                      W1, b1, W2, b2, eps, h);
    }

    pairwise_kernel<<<8192, 512, 0, stream>>>(h, out);
}

// Round 19
// 236.725 us; speedup vs baseline: 1.0312x; 1.0312x over previous
//
#include <hip/hip_runtime.h>

#define N_NODES 16384
#define N_EDGES 524288
#define TILE_I 16      // rows per block
#define TILE_J 2048    // 8 waves x 256 j
#define NBIN 256       // bins of 64 nodes
#define CAP 2560       // records per bin (avg 2048, sd ~45 -> 11 sigma)

typedef float f32x4 __attribute__((ext_vector_type(4)));

// ---------- Phase A: expand edges into per-bin record buffers ----------
// 1 edge/thread. LDS histogram -> one global cursor atomic per (block,bin),
// then plain 16B record stores {tgt, x[src].xyz}. No device-scope f32
// atomics (R17: cut prologue 66 -> 38 us vs atomic scatter).
__global__ __launch_bounds__(512) void binscatter_kernel(const int* __restrict__ eidx,
                                                         const float* __restrict__ x,
                                                         int* __restrict__ gcur,
                                                         float4* __restrict__ recs) {
    __shared__ int lcnt[NBIN];
    __shared__ int lbase[NBIN];
    const int tid = threadIdx.x;
    const int e = blockIdx.x * 512 + tid;

    if (tid < NBIN) lcnt[tid] = 0;
    __syncthreads();

    const int t = eidx[N_EDGES + e];
    const int s = eidx[e];
    const int bin = t >> 6;
    const float f0 = x[s * 3 + 0];
    const float f1 = x[s * 3 + 1];
    const float f2 = x[s * 3 + 2];
    atomicAdd(&lcnt[bin], 1);
    __syncthreads();

    if (tid < NBIN) {
        lbase[tid] = atomicAdd(&gcur[tid], lcnt[tid]);
        lcnt[tid] = 0;
    }
    __syncthreads();

    const int slot = lbase[bin] + atomicAdd(&lcnt[bin], 1);
    if (slot < CAP) {
        float4 r;
        r.x = __int_as_float(t);
        r.y = f0; r.z = f1; r.w = f2;
        recs[(size_t)bin * CAP + slot] = r;
    }
}

// ---------- Phase B: per-bin LDS reduction + fused GIN MLP ----------
__global__ __launch_bounds__(512) void binmlp_kernel(const float4* __restrict__ recs,
                                                     const int* __restrict__ gcur,
                                                     const float* __restrict__ x,
                                                     const float* __restrict__ W1,
                                                     const float* __restrict__ b1,
                                                     const float* __restrict__ W2,
                                                     const float* __restrict__ b2,
                                                     const float* __restrict__ eps_p,
                                                     float* __restrict__ h) {
    __shared__ float lagg[64 * 3];
    const int k = blockIdx.x;
    const int tid = threadIdx.x;

    if (tid < 192) lagg[tid] = 0.0f;
    __syncthreads();

    int cnt = gcur[k];
    if (cnt > CAP) cnt = CAP;
    for (int i = tid; i < cnt; i += 512) {
        const float4 r = recs[(size_t)k * CAP + i];
        const int d = __float_as_int(r.x) & 63;
        atomicAdd(&lagg[d * 3 + 0], r.y);
        atomicAdd(&lagg[d * 3 + 1], r.z);
        atomicAdd(&lagg[d * 3 + 2], r.w);
    }
    __syncthreads();

    if (tid < 64) {
        const int n = k * 64 + tid;
        const float se = 1.0f + eps_p[0];
        float z0 = se * x[n * 3 + 0] + lagg[tid * 3 + 0];
        float z1 = se * x[n * 3 + 1] + lagg[tid * 3 + 1];
        float z2 = se * x[n * 3 + 2] + lagg[tid * 3 + 2];
        float h1[16];
#pragma unroll
        for (int j = 0; j < 16; ++j) {
            float a = b1[j];
            a += z0 * W1[0 * 16 + j];
            a += z1 * W1[1 * 16 + j];
            a += z2 * W1[2 * 16 + j];
            h1[j] = fmaxf(a, 0.0f);
        }
        float4* h4 = (float4*)&h[(size_t)n * 16];
#pragma unroll
        for (int oq = 0; oq < 4; ++oq) {
            float4 o;
            float* op = (float*)&o;
#pragma unroll
            for (int c = 0; c < 4; ++c) {
                int oo = oq * 4 + c;
                float a = b2[oo];
#pragma unroll
                for (int j = 0; j < 16; ++j) a += h1[j] * W2[j * 16 + oo];
                op[c] = fmaxf(a, 0.0f);
            }
            h4[oq] = o;
        }
    }
}

// ---------- Fallback path: SoA scatter + separate MLP ----------
__global__ void scatter_kernel(const int* __restrict__ eidx,
                               const float* __restrict__ x,
                               float* __restrict__ agg0,
                               float* __restrict__ agg1,
                               float* __restrict__ agg2) {
    int e = blockIdx.x * blockDim.x + threadIdx.x;
    if (e >= N_EDGES) return;
    int s = eidx[e];
    int t = eidx[N_EDGES + e];
    atomicAdd(&agg0[t], x[s * 3 + 0]);
    atomicAdd(&agg1[t], x[s * 3 + 1]);
    atomicAdd(&agg2[t], x[s * 3 + 2]);
}

__global__ void mlp_kernel(const float* __restrict__ x,
                           const float* __restrict__ agg0,
                           const float* __restrict__ agg1,
                           const float* __restrict__ agg2,
                           const float* __restrict__ W1,
                           const float* __restrict__ b1,
                           const float* __restrict__ W2,
                           const float* __restrict__ b2,
                           const float* __restrict__ eps_p,
                           float* __restrict__ h) {
    int n = blockIdx.x * blockDim.x + threadIdx.x;
    if (n >= N_NODES) return;
    float se = 1.0f + eps_p[0];
    float z0 = se * x[n * 3 + 0] + agg0[n];
    float z1 = se * x[n * 3 + 1] + agg1[n];
    float z2 = se * x[n * 3 + 2] + agg2[n];
    float h1[16];
#pragma unroll
    for (int j = 0; j < 16; ++j) {
        float a = b1[j];
        a += z0 * W1[0 * 16 + j];
        a += z1 * W1[1 * 16 + j];
        a += z2 * W1[2 * 16 + j];
        h1[j] = fmaxf(a, 0.0f);
    }
    float4* h4 = (float4*)&h[n * 16];
#pragma unroll
    for (int oq = 0; oq < 4; ++oq) {
        float4 o;
        float* op = (float*)&o;
#pragma unroll
        for (int c = 0; c < 4; ++c) {
            int oo = oq * 4 + c;
            float a = b2[oo];
#pragma unroll
            for (int j = 0; j < 16; ++j) a += h1[j] * W2[j * 16 + oo];
            op[c] = fmaxf(a, 0.0f);
        }
        h4[oq] = o;
    }
}

// ---------------- pairwise: out[i][j] = dot(h[i], h[j]) ----------------
// R7/R17 kernel, byte-identical. 200 us @ 5.4 TB/s NT write. NT beats plain
// by ~6 us on this layout (R18 A/B); 7 structural variants all 200-216.
__global__ __launch_bounds__(512) void pairwise_kernel(const float* __restrict__ h,
                                                       float* __restrict__ out) {
    __shared__ float hi[TILE_I * 16];   // 1 KB
    const int i0 = (blockIdx.x >> 3) * TILE_I;
    const int j0 = (blockIdx.x & 7) * TILE_J;
    const int tid = threadIdx.x;
    const int wid = tid >> 6;
    const int lane = tid & 63;

    if (tid < TILE_I * 4) {
        ((f32x4*)hi)[tid] = ((const f32x4*)h)[(size_t)i0 * 4 + tid];
    }

    const int jbase = j0 + wid * 256 + lane * 4;
    const f32x4* hg = (const f32x4*)h;
    f32x4 hj[16];
#pragma unroll
    for (int jj = 0; jj < 4; ++jj) {
        const size_t jb4 = (size_t)(jbase + jj) * 4;
        f32x4 q0 = hg[jb4 + 0];
        f32x4 q1 = hg[jb4 + 1];
        f32x4 q2 = hg[jb4 + 2];
        f32x4 q3 = hg[jb4 + 3];
        hj[0][jj]  = q0.x;  hj[1][jj]  = q0.y;  hj[2][jj]  = q0.z;  hj[3][jj]  = q0.w;
        hj[4][jj]  = q1.x;  hj[5][jj]  = q1.y;  hj[6][jj]  = q1.z;  hj[7][jj]  = q1.w;
        hj[8][jj]  = q2.x;  hj[9][jj]  = q2.y;  hj[10][jj] = q2.z;  hj[11][jj] = q2.w;
        hj[12][jj] = q3.x;  hj[13][jj] = q3.y;  hj[14][jj] = q3.z;  hj[15][jj] = q3.w;
    }
    __syncthreads();

    f32x4* out4 = (f32x4*)out;
    const size_t obase = (size_t)i0 * (N_NODES / 4) + (size_t)(jbase >> 2);

#pragma unroll
    for (int r = 0; r < TILE_I; ++r) {
        const f32x4* hr = (const f32x4*)&hi[r * 16];
        f32x4 a0 = hr[0], a1 = hr[1], a2 = hr[2], a3 = hr[3];
        f32x4 acc = a0.x * hj[0];
        acc += a0.y * hj[1];
        acc += a0.z * hj[2];
        acc += a0.w * hj[3];
        acc += a1.x * hj[4];
        acc += a1.y * hj[5];
        acc += a1.z * hj[6];
        acc += a1.w * hj[7];
        acc += a2.x * hj[8];
        acc += a2.y * hj[9];
        acc += a2.z * hj[10];
        acc += a2.w * hj[11];
        acc += a3.x * hj[12];
        acc += a3.y * hj[13];
        acc += a3.z * hj[14];
        acc += a3.w * hj[15];
        __builtin_nontemporal_store(acc, &out4[obase + (size_t)r * (N_NODES / 4)]);
    }
}

extern "C" void kernel_launch(void* const* d_in, const int* in_sizes, int n_in,
                              void* d_out, int out_size, void* d_ws, size_t ws_size,
                              hipStream_t stream) {
    const float* node_feats = (const float*)d_in[0];
    const int*   edge_idx   = (const int*)d_in[1];
    const float* W1         = (const float*)d_in[2];
    const float* b1         = (const float*)d_in[3];
    const float* W2         = (const float*)d_in[4];
    const float* b2         = (const float*)d_in[5];
    const float* eps        = (const float*)d_in[6];
    float* out = (float*)d_out;

    // binned layout: gcur [256 ints] @0, h [1 MB] @4096, recs [10.5 MB] after
    int*    gcur = (int*)d_ws;
    float*  h    = (float*)((char*)d_ws + 4096);
    float4* recs = (float4*)((char*)d_ws + 4096 + (size_t)N_NODES * 16 * 4);
    const size_t need = 4096 + (size_t)N_NODES * 16 * 4
                      + (size_t)NBIN * CAP * sizeof(float4);

    if (ws_size >= need) {
        hipMemsetAsync(gcur, 0, NBIN * sizeof(int), stream);
        binscatter_kernel<<<N_EDGES / 512, 512, 0, stream>>>(edge_idx, node_feats,
                                                             gcur, recs);
        binmlp_kernel<<<NBIN, 512, 0, stream>>>(recs, gcur, node_feats,
                                                W1, b1, W2, b2, eps, h);
    } else {
        float* agg0 = (float*)((char*)d_ws + 4096 + (size_t)N_NODES * 16 * 4);
        float* agg1 = agg0 + N_NODES;
        float* agg2 = agg1 + N_NODES;
        hipMemsetAsync(agg0, 0, 3 * N_NODES * sizeof(float), stream);
        scatter_kernel<<<N_EDGES / 256, 256, 0, stream>>>(edge_idx, node_feats,
                                                          agg0, agg1, agg2);
        mlp_kernel<<<N_NODES / 256, 256, 0, stream>>>(node_feats, agg0, agg1, agg2,
                                                      W1, b1, W2, b2, eps, h);
    }

    pairwise_kernel<<<8192, 512, 0, stream>>>(h, out);
}